// Round 10
// baseline (1380.811 us; speedup 1.0000x reference)
//
#include <hip/hip_runtime.h>
#include <cstddef>

// Problem constants (reference: B=32, L=128, N=64, D=64, H=4, DH=16)
#define BB   32
#define LL   128
#define NN   64
#define DD   64
#define HH   4

typedef float v2f __attribute__((ext_vector_type(2)));

__device__ __forceinline__ float bcast(float v, int l) {
    return __int_as_float(__builtin_amdgcn_readlane(__float_as_int(v), l));
}
__device__ __forceinline__ float sigmoidf_(float x) {
    return 1.0f / (1.0f + __expf(-x));
}
__device__ __forceinline__ float tanhf_(float x) {
    float e = __expf(2.0f * x);
    return 1.0f - 2.0f / (e + 1.0f);
}

// ---------------------------------------------------------------------------
// R9 post-mortem: allocator keeps 64 wt floats/lane arch-VGPR-resident (R3,
// VGPR=84) but never 128+ (R5-R9: AGPR/scratch shuttling, 4x VALU inflation).
// So: 4 waves per chain-pair, each wave owns 16 k x 4 gate rows = 64 floats.
// h packed {b0,b1} in LDS -> uniform broadcast ds_read_b128 + v_pk_fma (2
// batches per inst). Partial gate sums exchanged via LDS once per step;
// waves 0/1 finalize batch 0/1 (nonlin + pooling/output), write h pairs back.
// ---------------------------------------------------------------------------
#define P8(X) X(0) X(1) X(2) X(3) X(4) X(5) X(6) X(7)
#define C4(a, e) ((e) == 0 ? (a).x : (e) == 1 ? (a).y : (e) == 2 ? (a).z : (a).w)

// One p covers k = 16w+2p (components .x/.y of hh) and k+1 (.z/.w).
#define KSTEP(p) {                                                            \
    const float4 hh = hp[kp0 + (p)];                                          \
    const v2f hA = {hh.x, hh.y}, hB = {hh.z, hh.w};                           \
    { const float a = C4(wi[(p) >> 1], ((p) & 1) * 2);                        \
      const float b = C4(wi[(p) >> 1], ((p) & 1) * 2 + 1);                    \
      aci = __builtin_elementwise_fma(v2f{a, a}, hA, aci);                    \
      aci = __builtin_elementwise_fma(v2f{b, b}, hB, aci); }                  \
    { const float a = C4(wf[(p) >> 1], ((p) & 1) * 2);                        \
      const float b = C4(wf[(p) >> 1], ((p) & 1) * 2 + 1);                    \
      acf = __builtin_elementwise_fma(v2f{a, a}, hA, acf);                    \
      acf = __builtin_elementwise_fma(v2f{b, b}, hB, acf); }                  \
    { const float a = C4(wg[(p) >> 1], ((p) & 1) * 2);                        \
      const float b = C4(wg[(p) >> 1], ((p) & 1) * 2 + 1);                    \
      acg = __builtin_elementwise_fma(v2f{a, a}, hA, acg);                    \
      acg = __builtin_elementwise_fma(v2f{b, b}, hB, acg); }                  \
    { const float a = C4(wo[(p) >> 1], ((p) & 1) * 2);                        \
      const float b = C4(wo[(p) >> 1], ((p) & 1) * 2 + 1);                    \
      aco = __builtin_elementwise_fma(v2f{a, a}, hA, aco);                    \
      aco = __builtin_elementwise_fma(v2f{b, b}, hB, aco); } }

// ---------------------------------------------------------------------------
// Encoder: block = (n, batch-pair), 4 waves = 4 k-teams. Online-softmax
// temporal attention pooling in the finalize waves.
// ---------------------------------------------------------------------------
__global__ __launch_bounds__(256, 4)
void enc_kernel(const float* __restrict__ X,
                const float* __restrict__ Wih,
                const float* __restrict__ Whh,
                const float* __restrict__ bias,
                const float* __restrict__ poolw,
                const float* __restrict__ poolb,
                float* __restrict__ Cws)   // [B][N][D]
{
    const int n   = blockIdx.x >> 4;
    const int bg  = blockIdx.x & 15;
    const int b0  = 2 * bg;
    const int tid = threadIdx.x;
    const int w   = tid >> 6;          // k-team; teams 0/1 also finalize batch 0/1
    const int u   = tid & 63;          // hidden unit
    const int kb  = w * 16;
    const int kp0 = w * 8;

    __shared__ __align__(16) float hl_sh[128];   // [kp][k2][b] = idx 2*u+b
    __shared__ float4 part[8][64];               // [2*w + b][u] = {i,f,g,o}
    __shared__ v2f   xs[LL];                     // {x_b0[t], x_b1[t]}

    // weights: 4 gate rows of unit u, k in [kb, kb+16)
    const float* Wr = Whh + ((size_t)n * 256 + u) * 64 + kb;
    float4 wi[4], wf[4], wg[4], wo[4];
#pragma unroll
    for (int q = 0; q < 4; ++q) {
        wi[q] = *(const float4*)(Wr + 4 * q);
        wf[q] = *(const float4*)(Wr + 64 * 64 + 4 * q);
        wg[q] = *(const float4*)(Wr + 128 * 64 + 4 * q);
        wo[q] = *(const float4*)(Wr + 192 * 64 + 4 * q);
    }

    const float* Bn = bias + n * 256;
    const float bi_ = Bn[u], bf_ = Bn[u + 64], bg_ = Bn[u + 128], bo_ = Bn[u + 192];
    const float* Wn = Wih + n * 256;
    const float wii = Wn[u], wif_ = Wn[u + 64], wig = Wn[u + 128], wio = Wn[u + 192];
    const float pwu = poolw[n * DD + u];
    const float pbn = poolb[n];

    // stage x pairs
    for (int i = tid; i < LL - 1; i += 256) {
        xs[i] = v2f{X[(size_t)b0 * (LL * NN) + (size_t)i * NN + n],
                    X[(size_t)(b0 + 1) * (LL * NN) + (size_t)i * NN + n]};
    }
    if (tid < 128) hl_sh[tid] = 0.0f;

    float cm = 0.0f, m = -1e30f, s_ = 0.0f, pa = 0.0f;
    __syncthreads();

    const float4* hp = (const float4*)hl_sh;

#pragma unroll 1
    for (int t = 0; t < LL - 1; ++t) {
        // ---- FMA phase: partial 4-gate pre-activations for both batches ----
        v2f aci, acf, acg, aco;
        if (w == 0) {
            const v2f x01 = xs[t];
            aci = __builtin_elementwise_fma(x01, v2f{wii, wii},  v2f{bi_, bi_});
            acf = __builtin_elementwise_fma(x01, v2f{wif_, wif_}, v2f{bf_, bf_});
            acg = __builtin_elementwise_fma(x01, v2f{wig, wig},  v2f{bg_, bg_});
            aco = __builtin_elementwise_fma(x01, v2f{wio, wio},  v2f{bo_, bo_});
        } else {
            aci = v2f{0.f, 0.f}; acf = v2f{0.f, 0.f};
            acg = v2f{0.f, 0.f}; aco = v2f{0.f, 0.f};
        }

        P8(KSTEP)

        part[2 * w + 0][u] = float4{aci.x, acf.x, acg.x, aco.x};
        part[2 * w + 1][u] = float4{aci.y, acf.y, acg.y, aco.y};
        __syncthreads();

        // ---- finalize: wave w<2 owns batch w ----
        if (w < 2) {
            const float4 ga = part[w][u],     gb = part[2 + w][u];
            const float4 gc = part[4 + w][u], gd = part[6 + w][u];
            const float gi = sigmoidf_(ga.x + gb.x + gc.x + gd.x);
            const float gf = sigmoidf_(ga.y + gb.y + gc.y + gd.y);
            const float gg = tanhf_   (ga.z + gb.z + gc.z + gd.z);
            const float go = sigmoidf_(ga.w + gb.w + gc.w + gd.w);
            cm = gf * cm + gi * gg;
            const float hm = go * tanhf_(cm);

            // temporal-attention pooling (online softmax), my batch
            float p = hm * pwu;
#pragma unroll
            for (int off = 32; off >= 1; off >>= 1) p += __shfl_xor(p, off, 64);
            const float score = p + pbn;
            const float mn   = fmaxf(m, score);
            const float corr = __expf(m - mn);
            const float wgt  = __expf(score - mn);
            s_ = s_ * corr + wgt;
            pa = pa * corr + wgt * hm;
            m  = mn;

            hl_sh[2 * u + w] = hm;
        }
        __syncthreads();
    }

    if (w < 2)
        Cws[(size_t)(b0 + w) * (NN * DD) + (size_t)n * DD + u] = pa / s_;
}

// ---------------------------------------------------------------------------
// Attention per (b, h): qkv slice -> scores -> softmax -> o head slice.
// ---------------------------------------------------------------------------
__global__ __launch_bounds__(256)
void attn_kernel(const float* __restrict__ Cws,
                 const float* __restrict__ Wqkv,
                 const float* __restrict__ bqkv,
                 float* __restrict__ Ows)
{
    const int b = blockIdx.x >> 2;
    const int h = blockIdx.x & 3;
    const int tid = threadIdx.x;

    __shared__ float Cl[64][65];
    __shared__ float Wl[48][65];
    __shared__ float biasl[48];
    __shared__ float ql[64][17], kl[64][17], vl[64][17];
    __shared__ float sl[64][65];

    for (int i = tid; i < 64 * 64; i += 256)
        Cl[i >> 6][i & 63] = Cws[(size_t)b * (NN * DD) + i];
    for (int i = tid; i < 48 * 64; i += 256) {
        int row = i >> 6, col = i & 63;
        int grp = row >> 4, r = row & 15;
        Wl[row][col] = Wqkv[(size_t)(grp * 64 + h * 16 + r) * DD + col];
    }
    if (tid < 48) {
        int grp = tid >> 4, r = tid & 15;
        biasl[tid] = bqkv[grp * 64 + h * 16 + r];
    }
    __syncthreads();

    for (int i = tid; i < 3 * 64 * 16; i += 256) {
        int sec = i >> 10;
        int rem = i & 1023;
        int nn = rem >> 4, dh = rem & 15;
        float acc = biasl[sec * 16 + dh];
        const float* wr = &Wl[sec * 16 + dh][0];
#pragma unroll 16
        for (int k = 0; k < 64; ++k) acc = fmaf(Cl[nn][k], wr[k], acc);
        if      (sec == 0) ql[nn][dh] = acc;
        else if (sec == 1) kl[nn][dh] = acc;
        else               vl[nn][dh] = acc;
    }
    __syncthreads();

    for (int i = tid; i < 64 * 64; i += 256) {
        int nn = i >> 6, mm = i & 63;
        float acc = 0.0f;
#pragma unroll
        for (int d = 0; d < 16; ++d) acc = fmaf(ql[nn][d], kl[mm][d], acc);
        sl[nn][mm] = acc * 0.25f;
    }
    __syncthreads();

    if (tid < 64) {
        float mx = -1e30f;
        for (int mm = 0; mm < 64; ++mm) mx = fmaxf(mx, sl[tid][mm]);
        float ss = 0.0f;
        for (int mm = 0; mm < 64; ++mm) {
            float e = __expf(sl[tid][mm] - mx);
            sl[tid][mm] = e;
            ss += e;
        }
        float inv = 1.0f / ss;
        for (int mm = 0; mm < 64; ++mm) sl[tid][mm] *= inv;
    }
    __syncthreads();

    for (int i = tid; i < 64 * 16; i += 256) {
        int nn = i >> 4, dh = i & 15;
        float acc = 0.0f;
#pragma unroll 16
        for (int mm = 0; mm < 64; ++mm) acc = fmaf(sl[nn][mm], vl[mm][dh], acc);
        Ows[(size_t)b * (NN * DD) + (size_t)nn * DD + h * 16 + dh] = acc;
    }
}

__global__ __launch_bounds__(256)
void proj_kernel(const float* __restrict__ Ows,
                 const float* __restrict__ Wo,
                 const float* __restrict__ bo,
                 float* __restrict__ Cstar)
{
    const int b = blockIdx.x;
    const int tid = threadIdx.x;
    __shared__ float Ol[64][65];
    __shared__ float Wl[64][65];

    for (int i = tid; i < 64 * 64; i += 256) {
        Ol[i >> 6][i & 63] = Ows[(size_t)b * (NN * DD) + i];
        Wl[i >> 6][i & 63] = Wo[i];
    }
    __syncthreads();

    for (int i = tid; i < 64 * 64; i += 256) {
        int nn = i >> 6, d = i & 63;
        float acc = bo[d];
#pragma unroll 16
        for (int k = 0; k < 64; ++k) acc = fmaf(Ol[nn][k], Wl[d][k], acc);
        Cstar[(size_t)b * (NN * DD) + i] = acc;
    }
}

// ---------------------------------------------------------------------------
// Decoder init: h0/c0 = tanh(Cs @ W^T + b) per (n, b). One wave per (n,b).
// ---------------------------------------------------------------------------
__global__ __launch_bounds__(64)
void dec_init_kernel(const float* __restrict__ Cstar,
                     const float* __restrict__ WhI,
                     const float* __restrict__ bhI,
                     const float* __restrict__ WcI,
                     const float* __restrict__ bcI,
                     float* __restrict__ H0,
                     float* __restrict__ C0)
{
    const int n = blockIdx.x >> 5;
    const int b = blockIdx.x & 31;
    const int u = threadIdx.x;

    const float cs = Cstar[(size_t)b * (NN * DD) + (size_t)n * DD + u];
    const float4* Rh = reinterpret_cast<const float4*>(WhI + ((size_t)n * DD + u) * DD);
    const float4* Rc = reinterpret_cast<const float4*>(WcI + ((size_t)n * DD + u) * DD);
    float ah = bhI[n * DD + u];
    float ac = bcI[n * DD + u];
#pragma unroll
    for (int q = 0; q < 16; ++q) {
        const float4 wh = Rh[q], wc = Rc[q];
        float k0 = bcast(cs, 4 * q + 0);
        float k1 = bcast(cs, 4 * q + 1);
        float k2 = bcast(cs, 4 * q + 2);
        float k3 = bcast(cs, 4 * q + 3);
        ah = fmaf(wh.x, k0, ah); ah = fmaf(wh.y, k1, ah);
        ah = fmaf(wh.z, k2, ah); ah = fmaf(wh.w, k3, ah);
        ac = fmaf(wc.x, k0, ac); ac = fmaf(wc.y, k1, ac);
        ac = fmaf(wc.z, k2, ac); ac = fmaf(wc.w, k3, ac);
    }
    const size_t idx = ((size_t)n * BB + b) * DD + u;
    H0[idx] = tanhf_(ah);
    C0[idx] = tanhf_(ac);
}

// ---------------------------------------------------------------------------
// Decoder: block = (n, batch-pair), 4 waves = 4 k-teams; zero inputs;
// per-step y = h.ow + ob from the finalize waves.
// ---------------------------------------------------------------------------
__global__ __launch_bounds__(256, 4)
void dec_kernel(const float* __restrict__ Whh,
                const float* __restrict__ bias,
                const float* __restrict__ ow,
                const float* __restrict__ ob,
                const float* __restrict__ H0,
                const float* __restrict__ C0,
                float* __restrict__ recon,        // [B][L-1][N]
                float* __restrict__ pred)         // [B][N]
{
    const int n   = blockIdx.x >> 4;
    const int bg  = blockIdx.x & 15;
    const int b0  = 2 * bg;
    const int tid = threadIdx.x;
    const int w   = tid >> 6;
    const int u   = tid & 63;
    const int kb  = w * 16;
    const int kp0 = w * 8;

    __shared__ __align__(16) float hl_sh[128];
    __shared__ float4 part[8][64];

    const float* Wr = Whh + ((size_t)n * 256 + u) * 64 + kb;
    float4 wi[4], wf[4], wg[4], wo[4];
#pragma unroll
    for (int q = 0; q < 4; ++q) {
        wi[q] = *(const float4*)(Wr + 4 * q);
        wf[q] = *(const float4*)(Wr + 64 * 64 + 4 * q);
        wg[q] = *(const float4*)(Wr + 128 * 64 + 4 * q);
        wo[q] = *(const float4*)(Wr + 192 * 64 + 4 * q);
    }

    const float* Bn = bias + n * 256;
    const float bi_ = Bn[u], bf_ = Bn[u + 64], bg_ = Bn[u + 128], bo_ = Bn[u + 192];
    const float owu = ow[n * DD + u];
    const float obn = ob[n];

    float cm = 0.0f;
    if (w < 2) {
        const size_t idx = ((size_t)n * BB + (b0 + w)) * DD + u;
        hl_sh[2 * u + w] = H0[idx];
        cm = C0[idx];
    }
    __syncthreads();

    const float4* hp = (const float4*)hl_sh;

#pragma unroll 1
    for (int t = 0; t < LL; ++t) {
        v2f aci, acf, acg, aco;
        if (w == 0) {
            aci = v2f{bi_, bi_}; acf = v2f{bf_, bf_};
            acg = v2f{bg_, bg_}; aco = v2f{bo_, bo_};
        } else {
            aci = v2f{0.f, 0.f}; acf = v2f{0.f, 0.f};
            acg = v2f{0.f, 0.f}; aco = v2f{0.f, 0.f};
        }

        P8(KSTEP)

        part[2 * w + 0][u] = float4{aci.x, acf.x, acg.x, aco.x};
        part[2 * w + 1][u] = float4{aci.y, acf.y, acg.y, aco.y};
        __syncthreads();

        if (w < 2) {
            const float4 ga = part[w][u],     gb = part[2 + w][u];
            const float4 gc = part[4 + w][u], gd = part[6 + w][u];
            const float gi = sigmoidf_(ga.x + gb.x + gc.x + gd.x);
            const float gf = sigmoidf_(ga.y + gb.y + gc.y + gd.y);
            const float gg = tanhf_   (ga.z + gb.z + gc.z + gd.z);
            const float go = sigmoidf_(ga.w + gb.w + gc.w + gd.w);
            cm = gf * cm + gi * gg;
            const float hm = go * tanhf_(cm);

            float p = hm * owu;
#pragma unroll
            for (int off = 32; off >= 1; off >>= 1) p += __shfl_xor(p, off, 64);
            if (u == 0) {
                const float y = p + obn;
                if (t < LL - 1)
                    recon[(size_t)(b0 + w) * ((LL - 1) * NN) + (size_t)t * NN + n] = y;
                else
                    pred[(size_t)(b0 + w) * NN + n] = y;
            }

            hl_sh[2 * u + w] = hm;
        }
        __syncthreads();
    }
}

extern "C" void kernel_launch(void* const* d_in, const int* in_sizes, int n_in,
                              void* d_out, int out_size, void* d_ws, size_t ws_size,
                              hipStream_t stream) {
    (void)in_sizes; (void)n_in; (void)out_size; (void)ws_size;

    const float* X         = (const float*)d_in[0];
    const float* enc_Wih   = (const float*)d_in[1];
    const float* enc_Whh   = (const float*)d_in[2];
    const float* enc_b     = (const float*)d_in[3];
    const float* pool_w    = (const float*)d_in[4];
    const float* pool_b    = (const float*)d_in[5];
    const float* attn_Wqkv = (const float*)d_in[6];
    const float* attn_bqkv = (const float*)d_in[7];
    const float* attn_Wo   = (const float*)d_in[8];
    const float* attn_bo   = (const float*)d_in[9];
    // d_in[10] = dec_Wih: multiplied by all-zero inputs -> unused
    const float* dec_Whh   = (const float*)d_in[11];
    const float* dec_b     = (const float*)d_in[12];
    const float* init_h_W  = (const float*)d_in[13];
    const float* init_h_b  = (const float*)d_in[14];
    const float* init_c_W  = (const float*)d_in[15];
    const float* init_c_b  = (const float*)d_in[16];
    const float* out_w     = (const float*)d_in[17];
    const float* out_b     = (const float*)d_in[18];

    float* out   = (float*)d_out;
    float* recon = out;                                     // B*(L-1)*N
    float* pred  = out + (size_t)BB * (LL - 1) * NN;        // B*N
    float* cstar = pred + (size_t)BB * NN;                  // B*N*D

    float* Cws = (float*)d_ws;                              // [B][N][D]
    float* Ows = Cws + (size_t)BB * NN * DD;                // [B][N][D]
    // After proj, Cws/Ows are dead -> reuse for H0/C0 ([N][B][D] each)
    float* H0 = Cws;
    float* C0 = Ows;

    enc_kernel<<<dim3(NN * 16), dim3(256), 0, stream>>>(
        X, enc_Wih, enc_Whh, enc_b, pool_w, pool_b, Cws);

    attn_kernel<<<dim3(BB * HH), dim3(256), 0, stream>>>(
        Cws, attn_Wqkv, attn_bqkv, Ows);

    proj_kernel<<<dim3(BB), dim3(256), 0, stream>>>(
        Ows, attn_Wo, attn_bo, cstar);

    dec_init_kernel<<<dim3(NN * BB), dim3(64), 0, stream>>>(
        cstar, init_h_W, init_h_b, init_c_W, init_c_b, H0, C0);

    dec_kernel<<<dim3(NN * 16), dim3(256), 0, stream>>>(
        dec_Whh, dec_b, out_w, out_b, H0, C0, recon, pred);
}

// Round 11
// 608.726 us; speedup vs baseline: 2.2684x; 2.2684x over previous
//
#include <hip/hip_runtime.h>
#include <cstddef>

// Problem constants (reference: B=32, L=128, N=64, D=64, H=4, DH=16)
#define BB   32
#define LL   128
#define NN   64
#define DD   64
#define HH   4

typedef float v2f __attribute__((ext_vector_type(2)));

__device__ __forceinline__ float bcast(float v, int l) {
    return __int_as_float(__builtin_amdgcn_readlane(__float_as_int(v), l));
}
__device__ __forceinline__ float sigmoidf_(float x) {
    return 1.0f / (1.0f + __expf(-x));
}
__device__ __forceinline__ float tanhf_(float x) {
    float e = __expf(2.0f * x);
    return 1.0f - 2.0f / (e + 1.0f);
}

// ---------------------------------------------------------------------------
// R10 post-mortem: float4 wi/wf/wg/wo[4] arrays under __launch_bounds__(256,4)
// went to SCRATCH (VGPR=64, 375MB FETCH + 184MB WRITE per dispatch = spill
// traffic in HBM, 768 GB/s). R3 proved the same 64-float/lane footprint stays
// resident under (256,2) (VGPR=84, no spill). Fix: (256,2) + 16 individually
// NAMED float4s (no alloca at all). Structure otherwise identical to R10.
// ---------------------------------------------------------------------------

#define DECLW float4 wi0, wi1, wi2, wi3, wf0, wf1, wf2, wf3, \
                     wg0, wg1, wg2, wg3, wo0, wo1, wo2, wo3;
#define LOADW4(G, base) \
    w##G##0 = *(const float4*)((base));      \
    w##G##1 = *(const float4*)((base) + 4);  \
    w##G##2 = *(const float4*)((base) + 8);  \
    w##G##3 = *(const float4*)((base) + 12);

// one gate's two packed FMAs for k-pair (cA,cB) of named reg w<G><q>
#define KG(G, q, cA, cB) \
    ac##G = __builtin_elementwise_fma(v2f{w##G##q.cA, w##G##q.cA}, hA, ac##G); \
    ac##G = __builtin_elementwise_fma(v2f{w##G##q.cB, w##G##q.cB}, hB, ac##G);

// p-th LDS h-pair read (k = 16w+2p, 16w+2p+1 for batches b0,b1), all 4 gates
#define KSTEP(p, q, cA, cB) {                                   \
    const float4 hh = hp[kp0 + (p)];                            \
    const v2f hA = {hh.x, hh.y}, hB = {hh.z, hh.w};             \
    KG(i, q, cA, cB) KG(f, q, cA, cB)                           \
    KG(g, q, cA, cB) KG(o, q, cA, cB) }

#define KSTEPS \
    KSTEP(0,0,x,y) KSTEP(1,0,z,w) KSTEP(2,1,x,y) KSTEP(3,1,z,w) \
    KSTEP(4,2,x,y) KSTEP(5,2,z,w) KSTEP(6,3,x,y) KSTEP(7,3,z,w)

// ---------------------------------------------------------------------------
// Encoder: block = (n, batch-pair), 4 waves = 4 k-teams (16 k each).
// h packed {b0,b1} in LDS -> uniform broadcast ds_read_b128 + v_pk_fma.
// Waves 0/1 finalize batch 0/1 (nonlinearity + online-softmax pooling).
// ---------------------------------------------------------------------------
__global__ __launch_bounds__(256, 2)
void enc_kernel(const float* __restrict__ X,
                const float* __restrict__ Wih,
                const float* __restrict__ Whh,
                const float* __restrict__ bias,
                const float* __restrict__ poolw,
                const float* __restrict__ poolb,
                float* __restrict__ Cws)   // [B][N][D]
{
    const int n   = blockIdx.x >> 4;
    const int bg  = blockIdx.x & 15;
    const int b0  = 2 * bg;
    const int tid = threadIdx.x;
    const int w   = tid >> 6;          // k-team; teams 0/1 also finalize batch 0/1
    const int u   = tid & 63;          // hidden unit
    const int kb  = w * 16;
    const int kp0 = w * 8;

    __shared__ __align__(16) float hl_sh[128];   // [u][b] = idx 2*u+b
    __shared__ float4 part[8][64];               // [2*w + b][u] = {i,f,g,o}
    __shared__ v2f   xs[LL];                     // {x_b0[t], x_b1[t]}

    // weights: 4 gate rows of unit u, k in [kb, kb+16) — 16 NAMED float4s
    const float* Wr = Whh + ((size_t)n * 256 + u) * 64 + kb;
    DECLW
    LOADW4(i, Wr)
    LOADW4(f, Wr + 64 * 64)
    LOADW4(g, Wr + 128 * 64)
    LOADW4(o, Wr + 192 * 64)

    const float* Bn = bias + n * 256;
    const float bi_ = Bn[u], bf_ = Bn[u + 64], bg_ = Bn[u + 128], bo_ = Bn[u + 192];
    const float* Wn = Wih + n * 256;
    const float wii = Wn[u], wif_ = Wn[u + 64], wig = Wn[u + 128], wio = Wn[u + 192];
    const float pwu = poolw[n * DD + u];
    const float pbn = poolb[n];

    // stage x pairs
    for (int i = tid; i < LL - 1; i += 256) {
        xs[i] = v2f{X[(size_t)b0 * (LL * NN) + (size_t)i * NN + n],
                    X[(size_t)(b0 + 1) * (LL * NN) + (size_t)i * NN + n]};
    }
    if (tid < 128) hl_sh[tid] = 0.0f;

    float cm = 0.0f, m = -1e30f, s_ = 0.0f, pa = 0.0f;
    __syncthreads();

    const float4* hp = (const float4*)hl_sh;

#pragma unroll 1
    for (int t = 0; t < LL - 1; ++t) {
        // ---- FMA phase: partial 4-gate pre-activations for both batches ----
        v2f aci, acf, acg, aco;
        if (w == 0) {
            const v2f x01 = xs[t];
            aci = __builtin_elementwise_fma(x01, v2f{wii, wii},  v2f{bi_, bi_});
            acf = __builtin_elementwise_fma(x01, v2f{wif_, wif_}, v2f{bf_, bf_});
            acg = __builtin_elementwise_fma(x01, v2f{wig, wig},  v2f{bg_, bg_});
            aco = __builtin_elementwise_fma(x01, v2f{wio, wio},  v2f{bo_, bo_});
        } else {
            aci = v2f{0.f, 0.f}; acf = v2f{0.f, 0.f};
            acg = v2f{0.f, 0.f}; aco = v2f{0.f, 0.f};
        }

        KSTEPS

        part[2 * w + 0][u] = float4{aci.x, acf.x, acg.x, aco.x};
        part[2 * w + 1][u] = float4{aci.y, acf.y, acg.y, aco.y};
        __syncthreads();

        // ---- finalize: wave w<2 owns batch w ----
        if (w < 2) {
            const float4 ga = part[w][u],     gb = part[2 + w][u];
            const float4 gc = part[4 + w][u], gd = part[6 + w][u];
            const float gi = sigmoidf_(ga.x + gb.x + gc.x + gd.x);
            const float gf = sigmoidf_(ga.y + gb.y + gc.y + gd.y);
            const float gg = tanhf_   (ga.z + gb.z + gc.z + gd.z);
            const float go = sigmoidf_(ga.w + gb.w + gc.w + gd.w);
            cm = gf * cm + gi * gg;
            const float hm = go * tanhf_(cm);

            // temporal-attention pooling (online softmax), my batch
            float p = hm * pwu;
#pragma unroll
            for (int off = 32; off >= 1; off >>= 1) p += __shfl_xor(p, off, 64);
            const float score = p + pbn;
            const float mn   = fmaxf(m, score);
            const float corr = __expf(m - mn);
            const float wgt  = __expf(score - mn);
            s_ = s_ * corr + wgt;
            pa = pa * corr + wgt * hm;
            m  = mn;

            hl_sh[2 * u + w] = hm;
        }
        __syncthreads();
    }

    if (w < 2)
        Cws[(size_t)(b0 + w) * (NN * DD) + (size_t)n * DD + u] = pa / s_;
}

// ---------------------------------------------------------------------------
// Attention per (b, h): qkv slice -> scores -> softmax -> o head slice.
// ---------------------------------------------------------------------------
__global__ __launch_bounds__(256)
void attn_kernel(const float* __restrict__ Cws,
                 const float* __restrict__ Wqkv,
                 const float* __restrict__ bqkv,
                 float* __restrict__ Ows)
{
    const int b = blockIdx.x >> 2;
    const int h = blockIdx.x & 3;
    const int tid = threadIdx.x;

    __shared__ float Cl[64][65];
    __shared__ float Wl[48][65];
    __shared__ float biasl[48];
    __shared__ float ql[64][17], kl[64][17], vl[64][17];
    __shared__ float sl[64][65];

    for (int i = tid; i < 64 * 64; i += 256)
        Cl[i >> 6][i & 63] = Cws[(size_t)b * (NN * DD) + i];
    for (int i = tid; i < 48 * 64; i += 256) {
        int row = i >> 6, col = i & 63;
        int grp = row >> 4, r = row & 15;
        Wl[row][col] = Wqkv[(size_t)(grp * 64 + h * 16 + r) * DD + col];
    }
    if (tid < 48) {
        int grp = tid >> 4, r = tid & 15;
        biasl[tid] = bqkv[grp * 64 + h * 16 + r];
    }
    __syncthreads();

    for (int i = tid; i < 3 * 64 * 16; i += 256) {
        int sec = i >> 10;
        int rem = i & 1023;
        int nn = rem >> 4, dh = rem & 15;
        float acc = biasl[sec * 16 + dh];
        const float* wr = &Wl[sec * 16 + dh][0];
#pragma unroll 16
        for (int k = 0; k < 64; ++k) acc = fmaf(Cl[nn][k], wr[k], acc);
        if      (sec == 0) ql[nn][dh] = acc;
        else if (sec == 1) kl[nn][dh] = acc;
        else               vl[nn][dh] = acc;
    }
    __syncthreads();

    for (int i = tid; i < 64 * 64; i += 256) {
        int nn = i >> 6, mm = i & 63;
        float acc = 0.0f;
#pragma unroll
        for (int d = 0; d < 16; ++d) acc = fmaf(ql[nn][d], kl[mm][d], acc);
        sl[nn][mm] = acc * 0.25f;
    }
    __syncthreads();

    if (tid < 64) {
        float mx = -1e30f;
        for (int mm = 0; mm < 64; ++mm) mx = fmaxf(mx, sl[tid][mm]);
        float ss = 0.0f;
        for (int mm = 0; mm < 64; ++mm) {
            float e = __expf(sl[tid][mm] - mx);
            sl[tid][mm] = e;
            ss += e;
        }
        float inv = 1.0f / ss;
        for (int mm = 0; mm < 64; ++mm) sl[tid][mm] *= inv;
    }
    __syncthreads();

    for (int i = tid; i < 64 * 16; i += 256) {
        int nn = i >> 4, dh = i & 15;
        float acc = 0.0f;
#pragma unroll 16
        for (int mm = 0; mm < 64; ++mm) acc = fmaf(sl[nn][mm], vl[mm][dh], acc);
        Ows[(size_t)b * (NN * DD) + (size_t)nn * DD + h * 16 + dh] = acc;
    }
}

__global__ __launch_bounds__(256)
void proj_kernel(const float* __restrict__ Ows,
                 const float* __restrict__ Wo,
                 const float* __restrict__ bo,
                 float* __restrict__ Cstar)
{
    const int b = blockIdx.x;
    const int tid = threadIdx.x;
    __shared__ float Ol[64][65];
    __shared__ float Wl[64][65];

    for (int i = tid; i < 64 * 64; i += 256) {
        Ol[i >> 6][i & 63] = Ows[(size_t)b * (NN * DD) + i];
        Wl[i >> 6][i & 63] = Wo[i];
    }
    __syncthreads();

    for (int i = tid; i < 64 * 64; i += 256) {
        int nn = i >> 6, d = i & 63;
        float acc = bo[d];
#pragma unroll 16
        for (int k = 0; k < 64; ++k) acc = fmaf(Ol[nn][k], Wl[d][k], acc);
        Cstar[(size_t)b * (NN * DD) + i] = acc;
    }
}

// ---------------------------------------------------------------------------
// Decoder init: h0/c0 = tanh(Cs @ W^T + b) per (n, b). One wave per (n,b).
// ---------------------------------------------------------------------------
__global__ __launch_bounds__(64)
void dec_init_kernel(const float* __restrict__ Cstar,
                     const float* __restrict__ WhI,
                     const float* __restrict__ bhI,
                     const float* __restrict__ WcI,
                     const float* __restrict__ bcI,
                     float* __restrict__ H0,
                     float* __restrict__ C0)
{
    const int n = blockIdx.x >> 5;
    const int b = blockIdx.x & 31;
    const int u = threadIdx.x;

    const float cs = Cstar[(size_t)b * (NN * DD) + (size_t)n * DD + u];
    const float4* Rh = reinterpret_cast<const float4*>(WhI + ((size_t)n * DD + u) * DD);
    const float4* Rc = reinterpret_cast<const float4*>(WcI + ((size_t)n * DD + u) * DD);
    float ah = bhI[n * DD + u];
    float ac = bcI[n * DD + u];
#pragma unroll
    for (int q = 0; q < 16; ++q) {
        const float4 wh = Rh[q], wc = Rc[q];
        float k0 = bcast(cs, 4 * q + 0);
        float k1 = bcast(cs, 4 * q + 1);
        float k2 = bcast(cs, 4 * q + 2);
        float k3 = bcast(cs, 4 * q + 3);
        ah = fmaf(wh.x, k0, ah); ah = fmaf(wh.y, k1, ah);
        ah = fmaf(wh.z, k2, ah); ah = fmaf(wh.w, k3, ah);
        ac = fmaf(wc.x, k0, ac); ac = fmaf(wc.y, k1, ac);
        ac = fmaf(wc.z, k2, ac); ac = fmaf(wc.w, k3, ac);
    }
    const size_t idx = ((size_t)n * BB + b) * DD + u;
    H0[idx] = tanhf_(ah);
    C0[idx] = tanhf_(ac);
}

// ---------------------------------------------------------------------------
// Decoder: block = (n, batch-pair), 4 waves = 4 k-teams; zero inputs;
// per-step y = h.ow + ob from the finalize waves.
// ---------------------------------------------------------------------------
__global__ __launch_bounds__(256, 2)
void dec_kernel(const float* __restrict__ Whh,
                const float* __restrict__ bias,
                const float* __restrict__ ow,
                const float* __restrict__ ob,
                const float* __restrict__ H0,
                const float* __restrict__ C0,
                float* __restrict__ recon,        // [B][L-1][N]
                float* __restrict__ pred)         // [B][N]
{
    const int n   = blockIdx.x >> 4;
    const int bg  = blockIdx.x & 15;
    const int b0  = 2 * bg;
    const int tid = threadIdx.x;
    const int w   = tid >> 6;
    const int u   = tid & 63;
    const int kb  = w * 16;
    const int kp0 = w * 8;

    __shared__ __align__(16) float hl_sh[128];
    __shared__ float4 part[8][64];

    const float* Wr = Whh + ((size_t)n * 256 + u) * 64 + kb;
    DECLW
    LOADW4(i, Wr)
    LOADW4(f, Wr + 64 * 64)
    LOADW4(g, Wr + 128 * 64)
    LOADW4(o, Wr + 192 * 64)

    const float* Bn = bias + n * 256;
    const float bi_ = Bn[u], bf_ = Bn[u + 64], bg_ = Bn[u + 128], bo_ = Bn[u + 192];
    const float owu = ow[n * DD + u];
    const float obn = ob[n];

    float cm = 0.0f;
    if (w < 2) {
        const size_t idx = ((size_t)n * BB + (b0 + w)) * DD + u;
        hl_sh[2 * u + w] = H0[idx];
        cm = C0[idx];
    }
    __syncthreads();

    const float4* hp = (const float4*)hl_sh;

#pragma unroll 1
    for (int t = 0; t < LL; ++t) {
        v2f aci, acf, acg, aco;
        if (w == 0) {
            aci = v2f{bi_, bi_}; acf = v2f{bf_, bf_};
            acg = v2f{bg_, bg_}; aco = v2f{bo_, bo_};
        } else {
            aci = v2f{0.f, 0.f}; acf = v2f{0.f, 0.f};
            acg = v2f{0.f, 0.f}; aco = v2f{0.f, 0.f};
        }

        KSTEPS

        part[2 * w + 0][u] = float4{aci.x, acf.x, acg.x, aco.x};
        part[2 * w + 1][u] = float4{aci.y, acf.y, acg.y, aco.y};
        __syncthreads();

        if (w < 2) {
            const float4 ga = part[w][u],     gb = part[2 + w][u];
            const float4 gc = part[4 + w][u], gd = part[6 + w][u];
            const float gi = sigmoidf_(ga.x + gb.x + gc.x + gd.x);
            const float gf = sigmoidf_(ga.y + gb.y + gc.y + gd.y);
            const float gg = tanhf_   (ga.z + gb.z + gc.z + gd.z);
            const float go = sigmoidf_(ga.w + gb.w + gc.w + gd.w);
            cm = gf * cm + gi * gg;
            const float hm = go * tanhf_(cm);

            float p = hm * owu;
#pragma unroll
            for (int off = 32; off >= 1; off >>= 1) p += __shfl_xor(p, off, 64);
            if (u == 0) {
                const float y = p + obn;
                if (t < LL - 1)
                    recon[(size_t)(b0 + w) * ((LL - 1) * NN) + (size_t)t * NN + n] = y;
                else
                    pred[(size_t)(b0 + w) * NN + n] = y;
            }

            hl_sh[2 * u + w] = hm;
        }
        __syncthreads();
    }
}

extern "C" void kernel_launch(void* const* d_in, const int* in_sizes, int n_in,
                              void* d_out, int out_size, void* d_ws, size_t ws_size,
                              hipStream_t stream) {
    (void)in_sizes; (void)n_in; (void)out_size; (void)ws_size;

    const float* X         = (const float*)d_in[0];
    const float* enc_Wih   = (const float*)d_in[1];
    const float* enc_Whh   = (const float*)d_in[2];
    const float* enc_b     = (const float*)d_in[3];
    const float* pool_w    = (const float*)d_in[4];
    const float* pool_b    = (const float*)d_in[5];
    const float* attn_Wqkv = (const float*)d_in[6];
    const float* attn_bqkv = (const float*)d_in[7];
    const float* attn_Wo   = (const float*)d_in[8];
    const float* attn_bo   = (const float*)d_in[9];
    // d_in[10] = dec_Wih: multiplied by all-zero inputs -> unused
    const float* dec_Whh   = (const float*)d_in[11];
    const float* dec_b     = (const float*)d_in[12];
    const float* init_h_W  = (const float*)d_in[13];
    const float* init_h_b  = (const float*)d_in[14];
    const float* init_c_W  = (const float*)d_in[15];
    const float* init_c_b  = (const float*)d_in[16];
    const float* out_w     = (const float*)d_in[17];
    const float* out_b     = (const float*)d_in[18];

    float* out   = (float*)d_out;
    float* recon = out;                                     // B*(L-1)*N
    float* pred  = out + (size_t)BB * (LL - 1) * NN;        // B*N
    float* cstar = pred + (size_t)BB * NN;                  // B*N*D

    float* Cws = (float*)d_ws;                              // [B][N][D]
    float* Ows = Cws + (size_t)BB * NN * DD;                // [B][N][D]
    // After proj, Cws/Ows are dead -> reuse for H0/C0 ([N][B][D] each)
    float* H0 = Cws;
    float* C0 = Ows;

    enc_kernel<<<dim3(NN * 16), dim3(256), 0, stream>>>(
        X, enc_Wih, enc_Whh, enc_b, pool_w, pool_b, Cws);

    attn_kernel<<<dim3(BB * HH), dim3(256), 0, stream>>>(
        Cws, attn_Wqkv, attn_bqkv, Ows);

    proj_kernel<<<dim3(BB), dim3(256), 0, stream>>>(
        Ows, attn_Wo, attn_bo, cstar);

    dec_init_kernel<<<dim3(NN * BB), dim3(64), 0, stream>>>(
        cstar, init_h_W, init_h_b, init_c_W, init_c_b, H0, C0);

    dec_kernel<<<dim3(NN * 16), dim3(256), 0, stream>>>(
        dec_Whh, dec_b, out_w, out_b, H0, C0, recon, pred);
}

// Round 12
// 496.318 us; speedup vs baseline: 2.7821x; 1.2265x over previous
//
#include <hip/hip_runtime.h>
#include <cstddef>

// Problem constants (reference: B=32, L=128, N=64, D=64, H=4, DH=16)
#define BB   32
#define LL   128
#define NN   64
#define DD   64
#define HH   4

typedef float v2f __attribute__((ext_vector_type(2)));

__device__ __forceinline__ float bcast(float v, int l) {
    return __int_as_float(__builtin_amdgcn_readlane(__float_as_int(v), l));
}
__device__ __forceinline__ float sigmoidf_(float x) {
    return 1.0f / (1.0f + __expf(-x));
}
__device__ __forceinline__ float tanhf_(float x) {
    float e = __expf(2.0f * x);
    return 1.0f - 2.0f / (e + 1.0f);
}
__device__ __forceinline__ v2f fma2(v2f a, v2f b, v2f c) {
    return __builtin_elementwise_fma(a, b, c);
}

// ---------------------------------------------------------------------------
// R11 post-mortem: batch-packed pk-FMA needs {w,w} splats (1 v_mov per FMA,
// 3x VALU inflation) and the float4 partial exchange was 8-way conflicted.
// R12 design: pack over K-PAIRS instead. acc{e,o} += {w2j,w2j+1} x {h2j,h2j+1}
// — both operands are consecutive registers (float4 weight loads; b128 reads
// of chain-major hl[c][k]) -> no splats, no partial sums. Lane = (gate=wave,
// unit=lane) owns a full 64-k gate row (the proven-resident 64-float/lane
// footprint, VGPR~92 under (256,2)); handles 2 chains; gate = acc.x+acc.y.
// Gate exchange gl[c][gt][u] and h-write hl[c][u] are stride-1 conflict-free;
// h reads are wave-uniform broadcasts. Bias + x*Wih fold into finalize waves.
// ---------------------------------------------------------------------------

#define DECLW16 float4 w0, w1, w2, w3, w4, w5, w6, w7, \
                       w8, w9, w10, w11, w12, w13, w14, w15;
#define LOADW16(base) \
    w0  = *(const float4*)((base) +  0); w1  = *(const float4*)((base) +  4); \
    w2  = *(const float4*)((base) +  8); w3  = *(const float4*)((base) + 12); \
    w4  = *(const float4*)((base) + 16); w5  = *(const float4*)((base) + 20); \
    w6  = *(const float4*)((base) + 24); w7  = *(const float4*)((base) + 28); \
    w8  = *(const float4*)((base) + 32); w9  = *(const float4*)((base) + 36); \
    w10 = *(const float4*)((base) + 40); w11 = *(const float4*)((base) + 44); \
    w12 = *(const float4*)((base) + 48); w13 = *(const float4*)((base) + 52); \
    w14 = *(const float4*)((base) + 56); w15 = *(const float4*)((base) + 60);

// j-th float4 k-group: 2 broadcast b128 reads + 4 pk-FMA, no splats
#define KJ(j) { \
    const float4 ha = h0p[j]; \
    const float4 hb = h1p[j]; \
    a0 = fma2(v2f{w##j.x, w##j.y}, v2f{ha.x, ha.y}, a0); \
    a0 = fma2(v2f{w##j.z, w##j.w}, v2f{ha.z, ha.w}, a0); \
    a1 = fma2(v2f{w##j.x, w##j.y}, v2f{hb.x, hb.y}, a1); \
    a1 = fma2(v2f{w##j.z, w##j.w}, v2f{hb.z, hb.w}, a1); }

#define KJALL KJ(0) KJ(1) KJ(2) KJ(3) KJ(4) KJ(5) KJ(6) KJ(7) \
              KJ(8) KJ(9) KJ(10) KJ(11) KJ(12) KJ(13) KJ(14) KJ(15)

// ---------------------------------------------------------------------------
// Encoder: block = (n, batch-pair), 4 waves = 4 gates. Waves 0/1 also
// finalize chains 0/1 (nonlinearity + online-softmax pooling).
// ---------------------------------------------------------------------------
__global__ __launch_bounds__(256, 2)
void enc_kernel(const float* __restrict__ X,
                const float* __restrict__ Wih,
                const float* __restrict__ Whh,
                const float* __restrict__ bias,
                const float* __restrict__ poolw,
                const float* __restrict__ poolb,
                float* __restrict__ Cws)   // [B][N][D]
{
    const int n   = blockIdx.x >> 4;
    const int bg  = blockIdx.x & 15;
    const int b0  = 2 * bg;
    const int tid = threadIdx.x;
    const int gt  = tid >> 6;          // gate (i,f,g,o); waves 0/1 finalize c=gt
    const int u   = tid & 63;          // unit / gate-row within gate

    __shared__ __align__(16) float hl[2][64];   // [chain][k]  (chain-major!)
    __shared__ float gl[2][4][64];              // [chain][gate][unit]
    __shared__ float xs[LL][2];                 // [t][chain]

    // full gate row (64 weights) in 16 named float4s
    const float* Wr = Whh + ((size_t)n * 256 + gt * 64 + u) * 64;
    DECLW16
    LOADW16(Wr)

    // finalize-wave constants: bias + input weight of all 4 gates of unit u
    const float* Bn = bias + n * 256;
    const float bI = Bn[u], bF = Bn[u + 64], bG = Bn[u + 128], bO = Bn[u + 192];
    const float* Wn = Wih + n * 256;
    const float xI = Wn[u], xF = Wn[u + 64], xG = Wn[u + 128], xO = Wn[u + 192];
    const float pwu = poolw[n * DD + u];
    const float pbn = poolb[n];

    // stage x for both chains
    for (int i = tid; i < (LL - 1) * 2; i += 256) {
        const int t = i >> 1, cc = i & 1;
        xs[t][cc] = X[(size_t)(b0 + cc) * (LL * NN) + (size_t)t * NN + n];
    }
    if (tid < 128) hl[tid >> 6][tid & 63] = 0.0f;

    float cm = 0.0f, m = -1e30f, s_ = 0.0f, pa = 0.0f;
    __syncthreads();

    const float4* h0p = (const float4*)&hl[0][0];
    const float4* h1p = (const float4*)&hl[1][0];

#pragma unroll 1
    for (int t = 0; t < LL - 1; ++t) {
        // ---- FMA phase (all 4 waves): full gate row x h, both chains ----
        v2f a0 = {0.0f, 0.0f}, a1 = {0.0f, 0.0f};
        KJALL
        gl[0][gt][u] = a0.x + a0.y;   // stride-1, conflict-free
        gl[1][gt][u] = a1.x + a1.y;
        __syncthreads();

        // ---- finalize (waves 0/1 = chains 0/1) ----
        if (gt < 2) {
            const int c = gt;
            const float xt = xs[t][c];
            const float gi = sigmoidf_(fmaf(xt, xI, bI) + gl[c][0][u]);
            const float gf = sigmoidf_(fmaf(xt, xF, bF) + gl[c][1][u]);
            const float gg = tanhf_   (fmaf(xt, xG, bG) + gl[c][2][u]);
            const float go = sigmoidf_(fmaf(xt, xO, bO) + gl[c][3][u]);
            cm = gf * cm + gi * gg;
            const float hm = go * tanhf_(cm);

            // temporal-attention pooling (online softmax)
            float p = hm * pwu;
#pragma unroll
            for (int off = 32; off >= 1; off >>= 1) p += __shfl_xor(p, off, 64);
            const float score = p + pbn;
            const float mn   = fmaxf(m, score);
            const float corr = __expf(m - mn);
            const float wgt  = __expf(score - mn);
            s_ = s_ * corr + wgt;
            pa = pa * corr + wgt * hm;
            m  = mn;

            hl[c][u] = hm;                // stride-1, conflict-free
        }
        __syncthreads();
    }

    if (gt < 2)
        Cws[(size_t)(b0 + gt) * (NN * DD) + (size_t)n * DD + u] = pa / s_;
}

// ---------------------------------------------------------------------------
// Attention per (b, h): qkv slice -> scores -> softmax -> o head slice.
// ---------------------------------------------------------------------------
__global__ __launch_bounds__(256)
void attn_kernel(const float* __restrict__ Cws,
                 const float* __restrict__ Wqkv,
                 const float* __restrict__ bqkv,
                 float* __restrict__ Ows)
{
    const int b = blockIdx.x >> 2;
    const int h = blockIdx.x & 3;
    const int tid = threadIdx.x;

    __shared__ float Cl[64][65];
    __shared__ float Wl[48][65];
    __shared__ float biasl[48];
    __shared__ float ql[64][17], kl[64][17], vl[64][17];
    __shared__ float sl[64][65];

    for (int i = tid; i < 64 * 64; i += 256)
        Cl[i >> 6][i & 63] = Cws[(size_t)b * (NN * DD) + i];
    for (int i = tid; i < 48 * 64; i += 256) {
        int row = i >> 6, col = i & 63;
        int grp = row >> 4, r = row & 15;
        Wl[row][col] = Wqkv[(size_t)(grp * 64 + h * 16 + r) * DD + col];
    }
    if (tid < 48) {
        int grp = tid >> 4, r = tid & 15;
        biasl[tid] = bqkv[grp * 64 + h * 16 + r];
    }
    __syncthreads();

    for (int i = tid; i < 3 * 64 * 16; i += 256) {
        int sec = i >> 10;
        int rem = i & 1023;
        int nn = rem >> 4, dh = rem & 15;
        float acc = biasl[sec * 16 + dh];
        const float* wr = &Wl[sec * 16 + dh][0];
#pragma unroll 16
        for (int k = 0; k < 64; ++k) acc = fmaf(Cl[nn][k], wr[k], acc);
        if      (sec == 0) ql[nn][dh] = acc;
        else if (sec == 1) kl[nn][dh] = acc;
        else               vl[nn][dh] = acc;
    }
    __syncthreads();

    for (int i = tid; i < 64 * 64; i += 256) {
        int nn = i >> 6, mm = i & 63;
        float acc = 0.0f;
#pragma unroll
        for (int d = 0; d < 16; ++d) acc = fmaf(ql[nn][d], kl[mm][d], acc);
        sl[nn][mm] = acc * 0.25f;
    }
    __syncthreads();

    if (tid < 64) {
        float mx = -1e30f;
        for (int mm = 0; mm < 64; ++mm) mx = fmaxf(mx, sl[tid][mm]);
        float ss = 0.0f;
        for (int mm = 0; mm < 64; ++mm) {
            float e = __expf(sl[tid][mm] - mx);
            sl[tid][mm] = e;
            ss += e;
        }
        float inv = 1.0f / ss;
        for (int mm = 0; mm < 64; ++mm) sl[tid][mm] *= inv;
    }
    __syncthreads();

    for (int i = tid; i < 64 * 16; i += 256) {
        int nn = i >> 4, dh = i & 15;
        float acc = 0.0f;
#pragma unroll 16
        for (int mm = 0; mm < 64; ++mm) acc = fmaf(sl[nn][mm], vl[mm][dh], acc);
        Ows[(size_t)b * (NN * DD) + (size_t)nn * DD + h * 16 + dh] = acc;
    }
}

__global__ __launch_bounds__(256)
void proj_kernel(const float* __restrict__ Ows,
                 const float* __restrict__ Wo,
                 const float* __restrict__ bo,
                 float* __restrict__ Cstar)
{
    const int b = blockIdx.x;
    const int tid = threadIdx.x;
    __shared__ float Ol[64][65];
    __shared__ float Wl[64][65];

    for (int i = tid; i < 64 * 64; i += 256) {
        Ol[i >> 6][i & 63] = Ows[(size_t)b * (NN * DD) + i];
        Wl[i >> 6][i & 63] = Wo[i];
    }
    __syncthreads();

    for (int i = tid; i < 64 * 64; i += 256) {
        int nn = i >> 6, d = i & 63;
        float acc = bo[d];
#pragma unroll 16
        for (int k = 0; k < 64; ++k) acc = fmaf(Ol[nn][k], Wl[d][k], acc);
        Cstar[(size_t)b * (NN * DD) + i] = acc;
    }
}

// ---------------------------------------------------------------------------
// Decoder init: h0/c0 = tanh(Cs @ W^T + b) per (n, b). One wave per (n,b).
// ---------------------------------------------------------------------------
__global__ __launch_bounds__(64)
void dec_init_kernel(const float* __restrict__ Cstar,
                     const float* __restrict__ WhI,
                     const float* __restrict__ bhI,
                     const float* __restrict__ WcI,
                     const float* __restrict__ bcI,
                     float* __restrict__ H0,
                     float* __restrict__ C0)
{
    const int n = blockIdx.x >> 5;
    const int b = blockIdx.x & 31;
    const int u = threadIdx.x;

    const float cs = Cstar[(size_t)b * (NN * DD) + (size_t)n * DD + u];
    const float4* Rh = reinterpret_cast<const float4*>(WhI + ((size_t)n * DD + u) * DD);
    const float4* Rc = reinterpret_cast<const float4*>(WcI + ((size_t)n * DD + u) * DD);
    float ah = bhI[n * DD + u];
    float ac = bcI[n * DD + u];
#pragma unroll
    for (int q = 0; q < 16; ++q) {
        const float4 wh = Rh[q], wc = Rc[q];
        float k0 = bcast(cs, 4 * q + 0);
        float k1 = bcast(cs, 4 * q + 1);
        float k2 = bcast(cs, 4 * q + 2);
        float k3 = bcast(cs, 4 * q + 3);
        ah = fmaf(wh.x, k0, ah); ah = fmaf(wh.y, k1, ah);
        ah = fmaf(wh.z, k2, ah); ah = fmaf(wh.w, k3, ah);
        ac = fmaf(wc.x, k0, ac); ac = fmaf(wc.y, k1, ac);
        ac = fmaf(wc.z, k2, ac); ac = fmaf(wc.w, k3, ac);
    }
    const size_t idx = ((size_t)n * BB + b) * DD + u;
    H0[idx] = tanhf_(ah);
    C0[idx] = tanhf_(ac);
}

// ---------------------------------------------------------------------------
// Decoder: block = (n, batch-pair), 4 waves = 4 gates; zero inputs;
// waves 0/1 finalize chains 0/1 and emit y = h.ow + ob.
// ---------------------------------------------------------------------------
__global__ __launch_bounds__(256, 2)
void dec_kernel(const float* __restrict__ Whh,
                const float* __restrict__ bias,
                const float* __restrict__ ow,
                const float* __restrict__ ob,
                const float* __restrict__ H0,
                const float* __restrict__ C0,
                float* __restrict__ recon,        // [B][L-1][N]
                float* __restrict__ pred)         // [B][N]
{
    const int n   = blockIdx.x >> 4;
    const int bg  = blockIdx.x & 15;
    const int b0  = 2 * bg;
    const int tid = threadIdx.x;
    const int gt  = tid >> 6;
    const int u   = tid & 63;

    __shared__ __align__(16) float hl[2][64];
    __shared__ float gl[2][4][64];

    const float* Wr = Whh + ((size_t)n * 256 + gt * 64 + u) * 64;
    DECLW16
    LOADW16(Wr)

    const float* Bn = bias + n * 256;
    const float bI = Bn[u], bF = Bn[u + 64], bG = Bn[u + 128], bO = Bn[u + 192];
    const float owu = ow[n * DD + u];
    const float obn = ob[n];

    float cm = 0.0f;
    if (gt < 2) {
        const size_t idx = ((size_t)n * BB + (b0 + gt)) * DD + u;
        hl[gt][u] = H0[idx];
        cm = C0[idx];
    }
    __syncthreads();

    const float4* h0p = (const float4*)&hl[0][0];
    const float4* h1p = (const float4*)&hl[1][0];

#pragma unroll 1
    for (int t = 0; t < LL; ++t) {
        v2f a0 = {0.0f, 0.0f}, a1 = {0.0f, 0.0f};
        KJALL
        gl[0][gt][u] = a0.x + a0.y;
        gl[1][gt][u] = a1.x + a1.y;
        __syncthreads();

        if (gt < 2) {
            const int c = gt;
            const float gi = sigmoidf_(bI + gl[c][0][u]);
            const float gf = sigmoidf_(bF + gl[c][1][u]);
            const float gg = tanhf_   (bG + gl[c][2][u]);
            const float go = sigmoidf_(bO + gl[c][3][u]);
            cm = gf * cm + gi * gg;
            const float hm = go * tanhf_(cm);

            float p = hm * owu;
#pragma unroll
            for (int off = 32; off >= 1; off >>= 1) p += __shfl_xor(p, off, 64);
            if (u == 0) {
                const float y = p + obn;
                if (t < LL - 1)
                    recon[(size_t)(b0 + c) * ((LL - 1) * NN) + (size_t)t * NN + n] = y;
                else
                    pred[(size_t)(b0 + c) * NN + n] = y;
            }

            hl[c][u] = hm;
        }
        __syncthreads();
    }
}

extern "C" void kernel_launch(void* const* d_in, const int* in_sizes, int n_in,
                              void* d_out, int out_size, void* d_ws, size_t ws_size,
                              hipStream_t stream) {
    (void)in_sizes; (void)n_in; (void)out_size; (void)ws_size;

    const float* X         = (const float*)d_in[0];
    const float* enc_Wih   = (const float*)d_in[1];
    const float* enc_Whh   = (const float*)d_in[2];
    const float* enc_b     = (const float*)d_in[3];
    const float* pool_w    = (const float*)d_in[4];
    const float* pool_b    = (const float*)d_in[5];
    const float* attn_Wqkv = (const float*)d_in[6];
    const float* attn_bqkv = (const float*)d_in[7];
    const float* attn_Wo   = (const float*)d_in[8];
    const float* attn_bo   = (const float*)d_in[9];
    // d_in[10] = dec_Wih: multiplied by all-zero inputs -> unused
    const float* dec_Whh   = (const float*)d_in[11];
    const float* dec_b     = (const float*)d_in[12];
    const float* init_h_W  = (const float*)d_in[13];
    const float* init_h_b  = (const float*)d_in[14];
    const float* init_c_W  = (const float*)d_in[15];
    const float* init_c_b  = (const float*)d_in[16];
    const float* out_w     = (const float*)d_in[17];
    const float* out_b     = (const float*)d_in[18];

    float* out   = (float*)d_out;
    float* recon = out;                                     // B*(L-1)*N
    float* pred  = out + (size_t)BB * (LL - 1) * NN;        // B*N
    float* cstar = pred + (size_t)BB * NN;                  // B*N*D

    float* Cws = (float*)d_ws;                              // [B][N][D]
    float* Ows = Cws + (size_t)BB * NN * DD;                // [B][N][D]
    // After proj, Cws/Ows are dead -> reuse for H0/C0 ([N][B][D] each)
    float* H0 = Cws;
    float* C0 = Ows;

    enc_kernel<<<dim3(NN * 16), dim3(256), 0, stream>>>(
        X, enc_Wih, enc_Whh, enc_b, pool_w, pool_b, Cws);

    attn_kernel<<<dim3(BB * HH), dim3(256), 0, stream>>>(
        Cws, attn_Wqkv, attn_bqkv, Ows);

    proj_kernel<<<dim3(BB), dim3(256), 0, stream>>>(
        Ows, attn_Wo, attn_bo, cstar);

    dec_init_kernel<<<dim3(NN * BB), dim3(64), 0, stream>>>(
        cstar, init_h_W, init_h_b, init_c_W, init_c_b, H0, C0);

    dec_kernel<<<dim3(NN * 16), dim3(256), 0, stream>>>(
        dec_Whh, dec_b, out_w, out_b, H0, C0, recon, pred);
}